// Round 3
// baseline (1937.942 us; speedup 1.0000x reference)
//
#include <hip/hip_runtime.h>
#include <math.h>

#define BB 256
#define SS 30
#define CC 62
#define LL 169
#define OG 64
#define OH 64
#define KK1 64
#define KK2 32
#define KK3 14
#define T12LEN 95    // 64+32-1
#define FLEN 108     // 64+32+14-2
#define XP 184       // bf16 LDS row pitch for x: 16B-aligned rows, dword stride 92%32=28 -> 2-way max
#define FP 108       // bf16 LDS row pitch for F: 216B rows, dword stride 54%32=22 -> conflict-free

__device__ __forceinline__ unsigned short f2bf(float f) {
    unsigned u = __float_as_uint(f);
    u += 0x7fffu + ((u >> 16) & 1u);        // RTNE
    return (unsigned short)(u >> 16);
}
__device__ __forceinline__ float bflo(unsigned v) { return __uint_as_float(v << 16); }
__device__ __forceinline__ float bfhi(unsigned v) { return __uint_as_float(v & 0xffff0000u); }

// ---------------- setup kernels ----------------

// T[c1][c0][k'] = pw1_w[c1,c0] * sum_{k2} dw2_w[c1,k2] * dw1_w[c0,k'-k2]
__global__ void k_setup_T(const float* __restrict__ dw1, const float* __restrict__ dw2,
                          const float* __restrict__ pw1, float* __restrict__ Tbuf) {
    int c1 = blockIdx.x / CC, c0 = blockIdx.x % CC;
    int kp = threadIdx.x;
    if (kp >= T12LEN) return;
    int k2lo = max(0, kp - (KK1 - 1));
    int k2hi = min(KK2 - 1, kp);
    float s = 0.f;
    for (int k2 = k2lo; k2 <= k2hi; ++k2)
        s += dw2[c1 * KK2 + k2] * dw1[c0 * KK1 + (kp - k2)];
    Tbuf[(c1 * CC + c0) * T12LEN + kp] = s * pw1[c1 * CC + c0];
}

// g23[c1][k3] = sum_{c2} pw3_w[61,c2] * pw2_w[c2,c1] * dw3_w[c2,k3]   and  beff
__global__ void k_setup_g(const float* __restrict__ pw2, const float* __restrict__ pw3,
                          const float* __restrict__ dw3,
                          const float* __restrict__ dw1b, const float* __restrict__ pw1w,
                          const float* __restrict__ pw1b,
                          const float* __restrict__ dw2, const float* __restrict__ dw2b,
                          const float* __restrict__ pw2b,
                          const float* __restrict__ dw3b, const float* __restrict__ pw3b,
                          float* __restrict__ g23, float* __restrict__ beff) {
    __shared__ float by2[CC], vals[CC];
    int tid = threadIdx.x;
    for (int idx = tid; idx < CC * KK3; idx += blockDim.x) {
        int c1 = idx / KK3, k3 = idx % KK3;
        float s = 0.f;
        for (int c2 = 0; c2 < CC; ++c2)
            s += pw3[61 * CC + c2] * pw2[c2 * CC + c1] * dw3[c2 * KK3 + k3];
        g23[idx] = s;
    }
    if (tid < CC) {
        int c1 = tid;
        float bz1 = pw1b[c1];
        for (int c0 = 0; c0 < CC; ++c0) bz1 += pw1w[c1 * CC + c0] * dw1b[c0];
        float s2 = 0.f;
        for (int k = 0; k < KK2; ++k) s2 += dw2[c1 * KK2 + k];
        by2[c1] = dw2b[c1] + bz1 * s2;
    }
    __syncthreads();
    if (tid < CC) {
        int c2 = tid;
        float bz2 = pw2b[c2];
        for (int c1 = 0; c1 < CC; ++c1) bz2 += pw2[c2 * CC + c1] * by2[c1];
        float s3 = 0.f;
        for (int k = 0; k < KK3; ++k) s3 += dw3[c2 * KK3 + k];
        vals[c2] = pw3[61 * CC + c2] * (dw3b[c2] + bz2 * s3);
    }
    __syncthreads();
    if (tid == 0) {
        float s = pw3b[61];
        for (int c2 = 0; c2 < CC; ++c2) s += vals[c2];
        *beff = s;
    }
}

// F[c0][o] = sum_{c1,k3} g23[c1,k3] * T[c1][c0][o-k3]   -> bf16 output
__global__ void k_setup_F(const float* __restrict__ Tbuf, const float* __restrict__ g23,
                          unsigned short* __restrict__ Fb) {
    __shared__ float gl[CC * KK3];
    int c0 = blockIdx.x;
    for (int i = threadIdx.x; i < CC * KK3; i += blockDim.x) gl[i] = g23[i];
    __syncthreads();
    int o = threadIdx.x;
    if (o >= FLEN) return;
    float s = 0.f;
    int k3hi = min(KK3 - 1, o);
    int k3lo = max(0, o - (T12LEN - 1));
    for (int c1 = 0; c1 < CC; ++c1) {
        const float* Trow = Tbuf + (c1 * CC + c0) * T12LEN;
        for (int k3 = k3lo; k3 <= k3hi; ++k3)
            s += gl[c1 * KK3 + k3] * Trow[o - k3];
    }
    Fb[c0 * FLEN + o] = f2bf(s);
}

// Wt[gate][i][f] = W_gate[f][i]  (first-64-col half, transposed)
__global__ void k_setup_Wt(const float* __restrict__ Wr, const float* __restrict__ Wu,
                           const float* __restrict__ Wc, float* __restrict__ Wt) {
    int gate = blockIdx.x;
    const float* W = gate == 0 ? Wr : (gate == 1 ? Wu : Wc);
    for (int idx = threadIdx.x; idx < OG * OH; idx += blockDim.x) {
        int i = idx >> 6, f = idx & 63;
        Wt[gate * OG * OH + idx] = W[f * (OG + OH) + i];
    }
}

// ---------------- main parallel phase: one block per (b,t) ----------------
__global__ __launch_bounds__(256, 4) void k_main(
        const float* __restrict__ x, const float* __restrict__ adj,
        const unsigned short* __restrict__ Fb, const float* __restrict__ beff_p,
        const float* __restrict__ gcnw, const float* __restrict__ gcnb,
        const float* __restrict__ Wtr,
        const float* __restrict__ Wrb, const float* __restrict__ br,
        const float* __restrict__ Wub, const float* __restrict__ bu,
        const float* __restrict__ Wcb, const float* __restrict__ bc,
        float* __restrict__ gates) {
    __shared__ __align__(16) unsigned short xt[CC * XP];   // 22816 B
    __shared__ __align__(16) unsigned short Fl[CC * FP];   // 13392 B
    __shared__ float dpart[4][64];
    __shared__ float adjt[CC];
    __shared__ float wx[170];
    __shared__ float gpart[4][OG];
    __shared__ float glds[OG];

    int bt = blockIdx.x;            // b*SS + t
    int b = bt / SS, t = bt % SS;
    int tid = threadIdx.x;
    const float* xg = x + (size_t)bt * (CC * LL);

    // stage x -> bf16 padded rows (flat float2 global reads, 8B-aligned for all bt)
    {
        const float2* xg2 = (const float2*)xg;
        for (int p = tid; p < (CC * LL) / 2; p += 256) {
            float2 v = xg2[p];
            int i0 = 2 * p;
            int c = i0 / LL;
            int l = i0 - c * LL;
            xt[c * XP + l] = f2bf(v.x);
            if (l == LL - 1) xt[(c + 1) * XP] = f2bf(v.y);
            else             xt[c * XP + l + 1] = f2bf(v.y);
        }
    }
    // stage F (bf16, 13392 B = 837 x 16B)
    {
        const uint4* Fg = (const uint4*)Fb;
        uint4* Fl4 = (uint4*)Fl;
        for (int i = tid; i < 837; i += 256) Fl4[i] = Fg[i];
    }
    __syncthreads();

    // ---- d_row: J=16 register-tiled correlation, one c per lane, circular window ----
    int lane = tid & 63, wid = tid >> 6;
    int jp = lane & 3, lg = lane >> 2;
    int c = wid * 16 + lg;          // 0..63
    int j0 = 16 * jp;
    float acc[16];
    #pragma unroll
    for (int k = 0; k < 16; ++k) acc[k] = 0.f;

    if (c < CC) {
        const unsigned short* xrow = xt + c * XP + j0;
        const unsigned short* frow = Fl + c * FP;
        float e[20];
        {
            uint4 a0 = *(const uint4*)(xrow);
            uint4 a1 = *(const uint4*)(xrow + 8);
            e[0]=bflo(a0.x); e[1]=bfhi(a0.x); e[2]=bflo(a0.y); e[3]=bfhi(a0.y);
            e[4]=bflo(a0.z); e[5]=bfhi(a0.z); e[6]=bflo(a0.w); e[7]=bfhi(a0.w);
            e[8]=bflo(a1.x); e[9]=bfhi(a1.x); e[10]=bflo(a1.y); e[11]=bfhi(a1.y);
            e[12]=bflo(a1.z); e[13]=bfhi(a1.z); e[14]=bflo(a1.w); e[15]=bfhi(a1.w);
        }
        #pragma unroll
        for (int m = 0; m < 27; ++m) {
            uint2 nv = *(const uint2*)(xrow + 16 + 4 * m);
            uint2 fv = *(const uint2*)(frow + 4 * m);
            float f0 = bflo(fv.x), f1 = bfhi(fv.x), f2 = bflo(fv.y), f3 = bfhi(fv.y);
            e[(16 + 4 * m) % 20] = bflo(nv.x);
            e[(17 + 4 * m) % 20] = bfhi(nv.x);
            e[(18 + 4 * m) % 20] = bflo(nv.y);
            e[(19 + 4 * m) % 20] = bfhi(nv.y);
            #pragma unroll
            for (int k = 0; k < 16; ++k)
                acc[k] += f0 * e[(4 * m + k) % 20] + f1 * e[(4 * m + k + 1) % 20]
                        + f2 * e[(4 * m + k + 2) % 20] + f3 * e[(4 * m + k + 3) % 20];
        }
    }
    // reduce over lg (lane bits 2..5)
    #pragma unroll
    for (int k = 0; k < 16; ++k) {
        acc[k] += __shfl_xor(acc[k], 4);
        acc[k] += __shfl_xor(acc[k], 8);
        acc[k] += __shfl_xor(acc[k], 16);
        acc[k] += __shfl_xor(acc[k], 32);
    }
    if (lg == 0) {
        #pragma unroll
        for (int k = 0; k < 16; ++k) dpart[wid][j0 + k] = acc[k];
    }
    __syncthreads();

    if (tid < CC) {
        float d = dpart[0][tid] + dpart[1][tid] + dpart[2][tid] + dpart[3][tid];
        float v = d + *beff_p + adj[61 * CC + tid];
        adjt[tid] = 1.f / (1.f + __expf(-v));
    }
    __syncthreads();

    // wx[l] = sum_j adjt[j] * x[j][l]  (packed bf16 pairs: lane li owns l=2li, 2li+1)
    if (tid < 85) {
        float s0 = 0.f, s1 = 0.f;
        #pragma unroll 2
        for (int j = 0; j < CC; ++j) {
            unsigned v = ((const unsigned*)(xt + j * XP))[tid];
            float aj = adjt[j];
            s0 += aj * bflo(v);
            s1 += aj * bfhi(v);
        }
        wx[2 * tid] = s0;
        wx[2 * tid + 1] = s1;
    }
    __syncthreads();

    // g[f] = gcn_b[f] + sum_l wx[l] * gcn_w[l,f]   (l split over 4 thread groups)
    {
        int f = tid & 63, lq = tid >> 6;
        float s = 0.f;
        for (int l = lq; l < LL; l += 4) s += wx[l] * gcnw[l * OG + f];
        gpart[lq][f] = s;
    }
    __syncthreads();
    if (tid < OG)
        glds[tid] = gcnb[tid] + gpart[0][tid] + gpart[1][tid] + gpart[2][tid] + gpart[3][tid];
    __syncthreads();

    // per-gate gf-half pre-activations (+ all biases), transposed weights
    if (tid < 3 * OH) {
        int gate = tid >> 6, f = tid & 63;
        const float* Wt = Wtr + gate * OG * OH;
        const float* Wb = gate == 0 ? Wrb : (gate == 1 ? Wub : Wcb);
        const float* bb = gate == 0 ? br  : (gate == 1 ? bu  : bc);
        float s = Wb[f] + bb[f];
        #pragma unroll 4
        for (int i = 0; i < OG; ++i) s += glds[i] * Wt[i * OH + f];
        gates[((size_t)(gate * SS + t) * BB + b) * OH + f] = s;
    }
}

// ---------------- sequential GRU scan over t: one block per batch row ----------------
__global__ __launch_bounds__(256) void k_scan(
        const float* __restrict__ gates,
        const float* __restrict__ Wr, const float* __restrict__ Wu, const float* __restrict__ Wc,
        float* __restrict__ out) {
    __shared__ float hl[OH], rhl[OH];
    int b = blockIdx.x;
    int tid = threadIdx.x;
    int f = tid >> 2, q = tid & 3;
    float wr[16], wu[16], wc[16];
    #pragma unroll
    for (int i = 0; i < 16; ++i) {
        int col = OG + q * 16 + i;
        wr[i] = Wr[f * (OG + OH) + col];
        wu[i] = Wu[f * (OG + OH) + col];
        wc[i] = Wc[f * (OG + OH) + col];
    }
    float h = 0.f;
    if (tid < OH) hl[tid] = 0.f;
    __syncthreads();
    const float* Gr = gates;
    const float* Gu = gates + (size_t)SS * BB * OH;
    const float* Gc = gates + (size_t)2 * SS * BB * OH;
    for (int t = 0; t < SS; ++t) {
        float gr = Gr[((size_t)t * BB + b) * OH + f];
        float gu = Gu[((size_t)t * BB + b) * OH + f];
        float gc = Gc[((size_t)t * BB + b) * OH + f];
        float rv = 0.f, uv = 0.f;
        #pragma unroll
        for (int i = 0; i < 16; ++i) {
            float hv = hl[q * 16 + i];
            rv += wr[i] * hv;
            uv += wu[i] * hv;
        }
        rv += __shfl_xor(rv, 1); rv += __shfl_xor(rv, 2);
        uv += __shfl_xor(uv, 1); uv += __shfl_xor(uv, 2);
        float r = 1.f / (1.f + __expf(-(rv + gr)));
        float u = 1.f / (1.f + __expf(-(uv + gu)));
        if (q == 0) rhl[f] = r * h;
        __syncthreads();
        float cv = 0.f;
        #pragma unroll
        for (int i = 0; i < 16; ++i) cv += wc[i] * rhl[q * 16 + i];
        cv += __shfl_xor(cv, 1); cv += __shfl_xor(cv, 2);
        float cc = tanhf(cv + gc);
        if (q == 0) {
            h = u * h + (1.f - u) * cc;
            hl[f] = h;
        }
        __syncthreads();
    }
    if (q == 0) out[b * OH + f] = h;
}

extern "C" void kernel_launch(void* const* d_in, const int* in_sizes, int n_in,
                              void* d_out, int out_size, void* d_ws, size_t ws_size,
                              hipStream_t stream) {
    const float* x    = (const float*)d_in[0];
    const float* adj  = (const float*)d_in[1];
    const float* dw1w = (const float*)d_in[2];
    const float* dw1b = (const float*)d_in[3];
    const float* pw1w = (const float*)d_in[4];
    const float* pw1b = (const float*)d_in[5];
    const float* dw2w = (const float*)d_in[6];
    const float* dw2b = (const float*)d_in[7];
    const float* pw2w = (const float*)d_in[8];
    const float* pw2b = (const float*)d_in[9];
    const float* dw3w = (const float*)d_in[10];
    const float* dw3b = (const float*)d_in[11];
    const float* pw3w = (const float*)d_in[12];
    const float* pw3b = (const float*)d_in[13];
    const float* gcnw = (const float*)d_in[14];
    const float* gcnb = (const float*)d_in[15];
    const float* Wrw  = (const float*)d_in[16];
    const float* Wrb  = (const float*)d_in[17];
    const float* Wuw  = (const float*)d_in[18];
    const float* Wub  = (const float*)d_in[19];
    const float* Wcw  = (const float*)d_in[20];
    const float* Wcb  = (const float*)d_in[21];
    const float* br   = (const float*)d_in[22];
    const float* bu   = (const float*)d_in[23];
    const float* bc   = (const float*)d_in[24];
    float* out = (float*)d_out;

    // workspace layout (bytes)
    char* ws = (char*)d_ws;
    float* Tbuf           = (float*)(ws + 0);              // 365180 floats
    float* g23            = (float*)(ws + 1460736);        // 868 floats
    float* beff           = (float*)(ws + 1464320);        // 1 float
    unsigned short* Fbuf  = (unsigned short*)(ws + 1464576); // 6696 bf16 (16B aligned)
    float* gates          = (float*)(ws + 1491456);        // 1474560 floats
    float* Wt             = (float*)(ws + 7389696);        // 12288 floats
    (void)ws_size; (void)in_sizes; (void)n_in; (void)out_size;

    k_setup_T<<<CC * CC, 128, 0, stream>>>(dw1w, dw2w, pw1w, Tbuf);
    k_setup_g<<<1, 1024, 0, stream>>>(pw2w, pw3w, dw3w, dw1b, pw1w, pw1b,
                                      dw2w, dw2b, pw2b, dw3b, pw3b, g23, beff);
    k_setup_F<<<CC, 128, 0, stream>>>(Tbuf, g23, Fbuf);
    k_setup_Wt<<<3, 256, 0, stream>>>(Wrw, Wuw, Wcw, Wt);
    k_main<<<BB * SS, 256, 0, stream>>>(x, adj, Fbuf, beff, gcnw, gcnb, Wt,
                                        Wrb, br, Wub, bu, Wcb, bc, gates);
    k_scan<<<BB, 256, 0, stream>>>(gates, Wrw, Wuw, Wcw, out);
}

// Round 4
// 1381.807 us; speedup vs baseline: 1.4025x; 1.4025x over previous
//
#include <hip/hip_runtime.h>
#include <math.h>

#define BB 256
#define SS 30
#define CC 62
#define LL 169
#define OG 64
#define OH 64
#define KK1 64
#define KK2 32
#define KK3 14
#define T12LEN 95    // 64+32-1
#define FLEN 108     // 64+32+14-2
#define XP 180       // bf16 LDS pitch for x: 90 dwords, 90%32=26 (gcd 2) -> 4 accesses/bank (optimal)
#define FP 108       // bf16 LDS pitch for F: 54 dwords, 54%32=22 (gcd 2) -> optimal

__device__ __forceinline__ unsigned short f2bf(float f) {
    unsigned u = __float_as_uint(f);
    u += 0x7fffu + ((u >> 16) & 1u);        // RTNE
    return (unsigned short)(u >> 16);
}
__device__ __forceinline__ float bflo(unsigned v) { return __uint_as_float(v << 16); }
__device__ __forceinline__ float bfhi(unsigned v) { return __uint_as_float(v & 0xffff0000u); }

// ---------------- setup kernels ----------------

// T[c1][c0][k'] = pw1_w[c1,c0] * sum_{k2} dw2_w[c1,k2] * dw1_w[c0,k'-k2]
__global__ void k_setup_T(const float* __restrict__ dw1, const float* __restrict__ dw2,
                          const float* __restrict__ pw1, float* __restrict__ Tbuf) {
    int c1 = blockIdx.x / CC, c0 = blockIdx.x % CC;
    int kp = threadIdx.x;
    if (kp >= T12LEN) return;
    int k2lo = max(0, kp - (KK1 - 1));
    int k2hi = min(KK2 - 1, kp);
    float s = 0.f;
    for (int k2 = k2lo; k2 <= k2hi; ++k2)
        s += dw2[c1 * KK2 + k2] * dw1[c0 * KK1 + (kp - k2)];
    Tbuf[(c1 * CC + c0) * T12LEN + kp] = s * pw1[c1 * CC + c0];
}

// g23[c1][k3] = sum_{c2} pw3_w[61,c2] * pw2_w[c2,c1] * dw3_w[c2,k3]   and  beff
__global__ void k_setup_g(const float* __restrict__ pw2, const float* __restrict__ pw3,
                          const float* __restrict__ dw3,
                          const float* __restrict__ dw1b, const float* __restrict__ pw1w,
                          const float* __restrict__ pw1b,
                          const float* __restrict__ dw2, const float* __restrict__ dw2b,
                          const float* __restrict__ pw2b,
                          const float* __restrict__ dw3b, const float* __restrict__ pw3b,
                          float* __restrict__ g23, float* __restrict__ beff) {
    __shared__ float by2[CC], vals[CC];
    int tid = threadIdx.x;
    for (int idx = tid; idx < CC * KK3; idx += blockDim.x) {
        int c1 = idx / KK3, k3 = idx % KK3;
        float s = 0.f;
        for (int c2 = 0; c2 < CC; ++c2)
            s += pw3[61 * CC + c2] * pw2[c2 * CC + c1] * dw3[c2 * KK3 + k3];
        g23[idx] = s;
    }
    if (tid < CC) {
        int c1 = tid;
        float bz1 = pw1b[c1];
        for (int c0 = 0; c0 < CC; ++c0) bz1 += pw1w[c1 * CC + c0] * dw1b[c0];
        float s2 = 0.f;
        for (int k = 0; k < KK2; ++k) s2 += dw2[c1 * KK2 + k];
        by2[c1] = dw2b[c1] + bz1 * s2;
    }
    __syncthreads();
    if (tid < CC) {
        int c2 = tid;
        float bz2 = pw2b[c2];
        for (int c1 = 0; c1 < CC; ++c1) bz2 += pw2[c2 * CC + c1] * by2[c1];
        float s3 = 0.f;
        for (int k = 0; k < KK3; ++k) s3 += dw3[c2 * KK3 + k];
        vals[c2] = pw3[61 * CC + c2] * (dw3b[c2] + bz2 * s3);
    }
    __syncthreads();
    if (tid == 0) {
        float s = pw3b[61];
        for (int c2 = 0; c2 < CC; ++c2) s += vals[c2];
        *beff = s;
    }
}

// F[c0][o] = sum_{c1,k3} g23[c1,k3] * T[c1][c0][o-k3]   -> bf16 output
__global__ void k_setup_F(const float* __restrict__ Tbuf, const float* __restrict__ g23,
                          unsigned short* __restrict__ Fb) {
    __shared__ float gl[CC * KK3];
    int c0 = blockIdx.x;
    for (int i = threadIdx.x; i < CC * KK3; i += blockDim.x) gl[i] = g23[i];
    __syncthreads();
    int o = threadIdx.x;
    if (o >= FLEN) return;
    float s = 0.f;
    int k3hi = min(KK3 - 1, o);
    int k3lo = max(0, o - (T12LEN - 1));
    for (int c1 = 0; c1 < CC; ++c1) {
        const float* Trow = Tbuf + (c1 * CC + c0) * T12LEN;
        for (int k3 = k3lo; k3 <= k3hi; ++k3)
            s += gl[c1 * KK3 + k3] * Trow[o - k3];
    }
    Fb[c0 * FLEN + o] = f2bf(s);
}

// Wt[gate][i][f] = W_gate[f][i]  (first-64-col half, transposed)
__global__ void k_setup_Wt(const float* __restrict__ Wr, const float* __restrict__ Wu,
                           const float* __restrict__ Wc, float* __restrict__ Wt) {
    int gate = blockIdx.x;
    const float* W = gate == 0 ? Wr : (gate == 1 ? Wu : Wc);
    for (int idx = threadIdx.x; idx < OG * OH; idx += blockDim.x) {
        int i = idx >> 6, f = idx & 63;
        Wt[gate * OG * OH + idx] = W[f * (OG + OH) + i];
    }
}

// ---------------- main parallel phase: one block per (b,t) ----------------
__global__ __launch_bounds__(256, 3) void k_main(
        const float* __restrict__ x, const float* __restrict__ adj,
        const unsigned short* __restrict__ Fb, const float* __restrict__ beff_p,
        const float* __restrict__ gcnw, const float* __restrict__ gcnb,
        const float* __restrict__ Wtr,
        const float* __restrict__ Wrb, const float* __restrict__ br,
        const float* __restrict__ Wub, const float* __restrict__ bu,
        const float* __restrict__ Wcb, const float* __restrict__ bc,
        float* __restrict__ gates) {
    __shared__ __align__(16) unsigned short xt[CC * XP];   // 22320 B
    __shared__ __align__(16) unsigned short Fl[CC * FP];   // 13392 B
    __shared__ float dpart[4][64];
    __shared__ float adjt[CC];
    __shared__ float wx[170];
    __shared__ float gpart[4][OG];
    __shared__ float glds[OG];

    int bt = blockIdx.x;            // b*SS + t
    int b = bt / SS, t = bt % SS;
    int tid = threadIdx.x;
    const float* xg = x + (size_t)bt * (CC * LL);

    // zero the row pads (l in [169,180))
    for (int i = tid; i < CC * (XP - LL); i += 256) {
        int c = i / (XP - LL), l = LL + (i - c * (XP - LL));
        xt[c * XP + l] = 0;
    }
    // stage x -> bf16 padded rows (flat float2 global reads, 8B-aligned for all bt)
    {
        const float2* xg2 = (const float2*)xg;
        for (int p = tid; p < (CC * LL) / 2; p += 256) {
            float2 v = xg2[p];
            int i0 = 2 * p;
            int c = i0 / LL;
            int l = i0 - c * LL;
            xt[c * XP + l] = f2bf(v.x);
            if (l == LL - 1) xt[(c + 1) * XP] = f2bf(v.y);
            else             xt[c * XP + l + 1] = f2bf(v.y);
        }
    }
    // stage F (bf16, 13392 B = 837 x 16B)
    {
        const uint4* Fg = (const uint4*)Fb;
        uint4* Fl4 = (uint4*)Fl;
        for (int i = tid; i < 837; i += 256) Fl4[i] = Fg[i];
    }
    __syncthreads();

    // ---- d_row: J=16 register-tiled correlation, one c per lane, shift-register window ----
    int lane = tid & 63, wid = tid >> 6;
    int jp = lane & 3, lg = lane >> 2;
    int c = wid * 16 + lg;          // 0..63
    int j0 = 16 * jp;
    float acc[16];
    #pragma unroll
    for (int k = 0; k < 16; ++k) acc[k] = 0.f;

    if (c < CC) {
        const unsigned short* xrow = xt + c * XP + j0;
        const unsigned short* frow = Fl + c * FP;
        float e[20];
        {
            uint2 a0 = *(const uint2*)(xrow);
            uint2 a1 = *(const uint2*)(xrow + 4);
            uint2 a2 = *(const uint2*)(xrow + 8);
            uint2 a3 = *(const uint2*)(xrow + 12);
            e[0]=bflo(a0.x);  e[1]=bfhi(a0.x);  e[2]=bflo(a0.y);  e[3]=bfhi(a0.y);
            e[4]=bflo(a1.x);  e[5]=bfhi(a1.x);  e[6]=bflo(a1.y);  e[7]=bfhi(a1.y);
            e[8]=bflo(a2.x);  e[9]=bfhi(a2.x);  e[10]=bflo(a2.y); e[11]=bfhi(a2.y);
            e[12]=bflo(a3.x); e[13]=bfhi(a3.x); e[14]=bflo(a3.y); e[15]=bfhi(a3.y);
        }
        #pragma unroll
        for (int m = 0; m < 27; ++m) {
            uint2 nv = *(const uint2*)(xrow + 16 + 4 * m);
            uint2 fv = *(const uint2*)(frow + 4 * m);
            float f0 = bflo(fv.x), f1 = bfhi(fv.x), f2 = bflo(fv.y), f3 = bfhi(fv.y);
            e[16] = bflo(nv.x); e[17] = bfhi(nv.x);
            e[18] = bflo(nv.y); e[19] = bfhi(nv.y);
            #pragma unroll
            for (int k = 0; k < 16; ++k)
                acc[k] += f0 * e[k] + f1 * e[k + 1] + f2 * e[k + 2] + f3 * e[k + 3];
            #pragma unroll
            for (int i = 0; i < 16; ++i) e[i] = e[i + 4];
        }
    }
    // reduce over lg (lane bits 2..5)
    #pragma unroll
    for (int k = 0; k < 16; ++k) {
        acc[k] += __shfl_xor(acc[k], 4);
        acc[k] += __shfl_xor(acc[k], 8);
        acc[k] += __shfl_xor(acc[k], 16);
        acc[k] += __shfl_xor(acc[k], 32);
    }
    if (lg == 0) {
        #pragma unroll
        for (int k = 0; k < 16; ++k) dpart[wid][j0 + k] = acc[k];
    }
    __syncthreads();

    if (tid < CC) {
        float d = dpart[0][tid] + dpart[1][tid] + dpart[2][tid] + dpart[3][tid];
        float v = d + *beff_p + adj[61 * CC + tid];
        adjt[tid] = 1.f / (1.f + __expf(-v));
    }
    __syncthreads();

    // wx[l] = sum_j adjt[j] * x[j][l]  (packed bf16 pairs: lane li owns l=2li, 2li+1)
    if (tid < 85) {
        float s0 = 0.f, s1 = 0.f;
        #pragma unroll 2
        for (int j = 0; j < CC; ++j) {
            unsigned v = ((const unsigned*)(xt + j * XP))[tid];
            float aj = adjt[j];
            s0 += aj * bflo(v);
            s1 += aj * bfhi(v);
        }
        wx[2 * tid] = s0;
        wx[2 * tid + 1] = s1;
    }
    __syncthreads();

    // g[f] = gcn_b[f] + sum_l wx[l] * gcn_w[l,f]   (l split over 4 thread groups)
    {
        int f = tid & 63, lq = tid >> 6;
        float s = 0.f;
        for (int l = lq; l < LL; l += 4) s += wx[l] * gcnw[l * OG + f];
        gpart[lq][f] = s;
    }
    __syncthreads();
    if (tid < OG)
        glds[tid] = gcnb[tid] + gpart[0][tid] + gpart[1][tid] + gpart[2][tid] + gpart[3][tid];
    __syncthreads();

    // per-gate gf-half pre-activations (+ all biases), transposed weights
    if (tid < 3 * OH) {
        int gate = tid >> 6, f = tid & 63;
        const float* Wt = Wtr + gate * OG * OH;
        const float* Wb = gate == 0 ? Wrb : (gate == 1 ? Wub : Wcb);
        const float* bb = gate == 0 ? br  : (gate == 1 ? bu  : bc);
        float s = Wb[f] + bb[f];
        #pragma unroll 4
        for (int i = 0; i < OG; ++i) s += glds[i] * Wt[i * OH + f];
        gates[((size_t)(gate * SS + t) * BB + b) * OH + f] = s;
    }
}

// ---------------- sequential GRU scan over t: one block per batch row ----------------
__global__ __launch_bounds__(256) void k_scan(
        const float* __restrict__ gates,
        const float* __restrict__ Wr, const float* __restrict__ Wu, const float* __restrict__ Wc,
        float* __restrict__ out) {
    __shared__ float hl[OH], rhl[OH];
    int b = blockIdx.x;
    int tid = threadIdx.x;
    int f = tid >> 2, q = tid & 3;
    float wr[16], wu[16], wc[16];
    #pragma unroll
    for (int i = 0; i < 16; ++i) {
        int col = OG + q * 16 + i;
        wr[i] = Wr[f * (OG + OH) + col];
        wu[i] = Wu[f * (OG + OH) + col];
        wc[i] = Wc[f * (OG + OH) + col];
    }
    float h = 0.f;
    if (tid < OH) hl[tid] = 0.f;
    __syncthreads();
    const float* Gr = gates;
    const float* Gu = gates + (size_t)SS * BB * OH;
    const float* Gc = gates + (size_t)2 * SS * BB * OH;
    for (int t = 0; t < SS; ++t) {
        float gr = Gr[((size_t)t * BB + b) * OH + f];
        float gu = Gu[((size_t)t * BB + b) * OH + f];
        float gc = Gc[((size_t)t * BB + b) * OH + f];
        float rv = 0.f, uv = 0.f;
        #pragma unroll
        for (int i = 0; i < 16; ++i) {
            float hv = hl[q * 16 + i];
            rv += wr[i] * hv;
            uv += wu[i] * hv;
        }
        rv += __shfl_xor(rv, 1); rv += __shfl_xor(rv, 2);
        uv += __shfl_xor(uv, 1); uv += __shfl_xor(uv, 2);
        float r = 1.f / (1.f + __expf(-(rv + gr)));
        float u = 1.f / (1.f + __expf(-(uv + gu)));
        if (q == 0) rhl[f] = r * h;
        __syncthreads();
        float cv = 0.f;
        #pragma unroll
        for (int i = 0; i < 16; ++i) cv += wc[i] * rhl[q * 16 + i];
        cv += __shfl_xor(cv, 1); cv += __shfl_xor(cv, 2);
        float cc = tanhf(cv + gc);
        if (q == 0) {
            h = u * h + (1.f - u) * cc;
            hl[f] = h;
        }
        __syncthreads();
    }
    if (q == 0) out[b * OH + f] = h;
}

extern "C" void kernel_launch(void* const* d_in, const int* in_sizes, int n_in,
                              void* d_out, int out_size, void* d_ws, size_t ws_size,
                              hipStream_t stream) {
    const float* x    = (const float*)d_in[0];
    const float* adj  = (const float*)d_in[1];
    const float* dw1w = (const float*)d_in[2];
    const float* dw1b = (const float*)d_in[3];
    const float* pw1w = (const float*)d_in[4];
    const float* pw1b = (const float*)d_in[5];
    const float* dw2w = (const float*)d_in[6];
    const float* dw2b = (const float*)d_in[7];
    const float* pw2w = (const float*)d_in[8];
    const float* pw2b = (const float*)d_in[9];
    const float* dw3w = (const float*)d_in[10];
    const float* dw3b = (const float*)d_in[11];
    const float* pw3w = (const float*)d_in[12];
    const float* pw3b = (const float*)d_in[13];
    const float* gcnw = (const float*)d_in[14];
    const float* gcnb = (const float*)d_in[15];
    const float* Wrw  = (const float*)d_in[16];
    const float* Wrb  = (const float*)d_in[17];
    const float* Wuw  = (const float*)d_in[18];
    const float* Wub  = (const float*)d_in[19];
    const float* Wcw  = (const float*)d_in[20];
    const float* Wcb  = (const float*)d_in[21];
    const float* br   = (const float*)d_in[22];
    const float* bu   = (const float*)d_in[23];
    const float* bc   = (const float*)d_in[24];
    float* out = (float*)d_out;

    // workspace layout (bytes)
    char* ws = (char*)d_ws;
    float* Tbuf           = (float*)(ws + 0);              // 365180 floats
    float* g23            = (float*)(ws + 1460736);        // 868 floats
    float* beff           = (float*)(ws + 1464320);        // 1 float
    unsigned short* Fbuf  = (unsigned short*)(ws + 1464576); // 6696 bf16 (16B aligned)
    float* gates          = (float*)(ws + 1491456);        // 1474560 floats
    float* Wt             = (float*)(ws + 7389696);        // 12288 floats
    (void)ws_size; (void)in_sizes; (void)n_in; (void)out_size;

    k_setup_T<<<CC * CC, 128, 0, stream>>>(dw1w, dw2w, pw1w, Tbuf);
    k_setup_g<<<1, 1024, 0, stream>>>(pw2w, pw3w, dw3w, dw1b, pw1w, pw1b,
                                      dw2w, dw2b, pw2b, dw3b, pw3b, g23, beff);
    k_setup_F<<<CC, 128, 0, stream>>>(Tbuf, g23, Fbuf);
    k_setup_Wt<<<3, 256, 0, stream>>>(Wrw, Wuw, Wcw, Wt);
    k_main<<<BB * SS, 256, 0, stream>>>(x, adj, Fbuf, beff, gcnw, gcnb, Wt,
                                        Wrb, br, Wub, bu, Wcb, bc, gates);
    k_scan<<<BB, 256, 0, stream>>>(gates, Wrw, Wuw, Wcw, out);
}

// Round 5
// 421.218 us; speedup vs baseline: 4.6008x; 3.2805x over previous
//
#include <hip/hip_runtime.h>
#include <math.h>

#define BB 256
#define SS 30
#define CC 62
#define LL 169
#define OG 64
#define OH 64
#define KK1 64
#define KK2 32
#define KK3 14
#define T12LEN 95    // 64+32-1
#define FLEN 108     // 64+32+14-2
#define XP 180       // bf16 LDS pitch for x: 90 dwords, 90%32=26 (gcd 2)
#define FP 108       // bf16 LDS pitch for F: 54 dwords, 54%32=22 (gcd 2) -> conflict-free row spread

__device__ __forceinline__ unsigned short f2bf(float f) {
    unsigned u = __float_as_uint(f);
    u += 0x7fffu + ((u >> 16) & 1u);        // RTNE
    return (unsigned short)(u >> 16);
}
__device__ __forceinline__ float bflo(unsigned v) { return __uint_as_float(v << 16); }
__device__ __forceinline__ float bfhi(unsigned v) { return __uint_as_float(v & 0xffff0000u); }

// ---------------- setup kernels ----------------

// T[c1][c0][k'] = pw1_w[c1,c0] * sum_{k2} dw2_w[c1,k2] * dw1_w[c0,k'-k2]
__global__ void k_setup_T(const float* __restrict__ dw1, const float* __restrict__ dw2,
                          const float* __restrict__ pw1, float* __restrict__ Tbuf) {
    int c1 = blockIdx.x / CC, c0 = blockIdx.x % CC;
    int kp = threadIdx.x;
    if (kp >= T12LEN) return;
    int k2lo = max(0, kp - (KK1 - 1));
    int k2hi = min(KK2 - 1, kp);
    float s = 0.f;
    for (int k2 = k2lo; k2 <= k2hi; ++k2)
        s += dw2[c1 * KK2 + k2] * dw1[c0 * KK1 + (kp - k2)];
    Tbuf[(c1 * CC + c0) * T12LEN + kp] = s * pw1[c1 * CC + c0];
}

// g23[c1][k3] = sum_{c2} pw3_w[61,c2] * pw2_w[c2,c1] * dw3_w[c2,k3]   and  beff
__global__ void k_setup_g(const float* __restrict__ pw2, const float* __restrict__ pw3,
                          const float* __restrict__ dw3,
                          const float* __restrict__ dw1b, const float* __restrict__ pw1w,
                          const float* __restrict__ pw1b,
                          const float* __restrict__ dw2, const float* __restrict__ dw2b,
                          const float* __restrict__ pw2b,
                          const float* __restrict__ dw3b, const float* __restrict__ pw3b,
                          float* __restrict__ g23, float* __restrict__ beff) {
    __shared__ float by2[CC], vals[CC];
    int tid = threadIdx.x;
    for (int idx = tid; idx < CC * KK3; idx += blockDim.x) {
        int c1 = idx / KK3, k3 = idx % KK3;
        float s = 0.f;
        for (int c2 = 0; c2 < CC; ++c2)
            s += pw3[61 * CC + c2] * pw2[c2 * CC + c1] * dw3[c2 * KK3 + k3];
        g23[idx] = s;
    }
    if (tid < CC) {
        int c1 = tid;
        float bz1 = pw1b[c1];
        for (int c0 = 0; c0 < CC; ++c0) bz1 += pw1w[c1 * CC + c0] * dw1b[c0];
        float s2 = 0.f;
        for (int k = 0; k < KK2; ++k) s2 += dw2[c1 * KK2 + k];
        by2[c1] = dw2b[c1] + bz1 * s2;
    }
    __syncthreads();
    if (tid < CC) {
        int c2 = tid;
        float bz2 = pw2b[c2];
        for (int c1 = 0; c1 < CC; ++c1) bz2 += pw2[c2 * CC + c1] * by2[c1];
        float s3 = 0.f;
        for (int k = 0; k < KK3; ++k) s3 += dw3[c2 * KK3 + k];
        vals[c2] = pw3[61 * CC + c2] * (dw3b[c2] + bz2 * s3);
    }
    __syncthreads();
    if (tid == 0) {
        float s = pw3b[61];
        for (int c2 = 0; c2 < CC; ++c2) s += vals[c2];
        *beff = s;
    }
}

// F[c0][o] = sum_{c1,k3} g23[c1,k3] * T[c1][c0][o-k3]   -> bf16 output
__global__ void k_setup_F(const float* __restrict__ Tbuf, const float* __restrict__ g23,
                          unsigned short* __restrict__ Fb) {
    __shared__ float gl[CC * KK3];
    int c0 = blockIdx.x;
    for (int i = threadIdx.x; i < CC * KK3; i += blockDim.x) gl[i] = g23[i];
    __syncthreads();
    int o = threadIdx.x;
    if (o >= FLEN) return;
    float s = 0.f;
    int k3hi = min(KK3 - 1, o);
    int k3lo = max(0, o - (T12LEN - 1));
    for (int c1 = 0; c1 < CC; ++c1) {
        const float* Trow = Tbuf + (c1 * CC + c0) * T12LEN;
        for (int k3 = k3lo; k3 <= k3hi; ++k3)
            s += gl[c1 * KK3 + k3] * Trow[o - k3];
    }
    Fb[c0 * FLEN + o] = f2bf(s);
}

// Wt[gate][i][f] = W_gate[f][i]  (first-64-col half, transposed)
__global__ void k_setup_Wt(const float* __restrict__ Wr, const float* __restrict__ Wu,
                           const float* __restrict__ Wc, float* __restrict__ Wt) {
    int gate = blockIdx.x;
    const float* W = gate == 0 ? Wr : (gate == 1 ? Wu : Wc);
    for (int idx = threadIdx.x; idx < OG * OH; idx += blockDim.x) {
        int i = idx >> 6, f = idx & 63;
        Wt[gate * OG * OH + idx] = W[f * (OG + OH) + i];
    }
}

// accumulate one channel's correlation into acc[8]
__device__ __forceinline__ void corr_row(const unsigned short* __restrict__ xrow,
                                         const unsigned short* __restrict__ frow,
                                         float acc[8]) {
    float e[12];
    {
        uint2 a0 = *(const uint2*)(xrow);
        uint2 a1 = *(const uint2*)(xrow + 4);
        e[0]=bflo(a0.x); e[1]=bfhi(a0.x); e[2]=bflo(a0.y); e[3]=bfhi(a0.y);
        e[4]=bflo(a1.x); e[5]=bfhi(a1.x); e[6]=bflo(a1.y); e[7]=bfhi(a1.y);
    }
    #pragma unroll 9
    for (int m = 0; m < 27; ++m) {
        uint2 nv = *(const uint2*)(xrow + 8 + 4 * m);
        uint2 fv = *(const uint2*)(frow + 4 * m);
        float f0 = bflo(fv.x), f1 = bfhi(fv.x), f2 = bflo(fv.y), f3 = bfhi(fv.y);
        e[8]  = bflo(nv.x); e[9]  = bfhi(nv.x);
        e[10] = bflo(nv.y); e[11] = bfhi(nv.y);
        #pragma unroll
        for (int k = 0; k < 8; ++k)
            acc[k] += f0 * e[k] + f1 * e[k + 1] + f2 * e[k + 2] + f3 * e[k + 3];
        #pragma unroll
        for (int i = 0; i < 8; ++i) e[i] = e[i + 4];
    }
}

// ---------------- main parallel phase: one block per (b,t) ----------------
__global__ __launch_bounds__(256, 3) void k_main(
        const float* __restrict__ x, const float* __restrict__ adj,
        const unsigned short* __restrict__ Fb, const float* __restrict__ beff_p,
        const float* __restrict__ gcnw, const float* __restrict__ gcnb,
        const float* __restrict__ Wtr,
        const float* __restrict__ Wrb, const float* __restrict__ br,
        const float* __restrict__ Wub, const float* __restrict__ bu,
        const float* __restrict__ Wcb, const float* __restrict__ bc,
        float* __restrict__ gates) {
    __shared__ __align__(16) unsigned short xt[CC * XP];   // 22320 B
    __shared__ __align__(16) unsigned short Fl[CC * FP];   // 13392 B
    __shared__ float dpart[4][64];
    __shared__ float adjt[CC];
    __shared__ float wx[170];
    __shared__ float gpart[4][OG];
    __shared__ float glds[OG];

    int bt = blockIdx.x;            // b*SS + t
    int b = bt / SS, t = bt % SS;
    int tid = threadIdx.x;
    const float* xg = x + (size_t)bt * (CC * LL);

    // zero the row pads (l in [169,180))
    for (int i = tid; i < CC * (XP - LL); i += 256) {
        int c = i / (XP - LL), l = LL + (i - c * (XP - LL));
        xt[c * XP + l] = 0;
    }
    // stage x -> bf16 padded rows (flat float2 global reads, 8B-aligned for all bt)
    {
        const float2* xg2 = (const float2*)xg;
        for (int p = tid; p < (CC * LL) / 2; p += 256) {
            float2 v = xg2[p];
            int i0 = 2 * p;
            int c = i0 / LL;
            int l = i0 - c * LL;
            xt[c * XP + l] = f2bf(v.x);
            if (l == LL - 1) xt[(c + 1) * XP] = f2bf(v.y);
            else             xt[c * XP + l + 1] = f2bf(v.y);
        }
    }
    // stage F (bf16, 13392 B = 837 x 16B)
    {
        const uint4* Fg = (const uint4*)Fb;
        uint4* Fl4 = (uint4*)Fl;
        for (int i = tid; i < 837; i += 256) Fl4[i] = Fg[i];
    }
    __syncthreads();

    // ---- d_row: J=8 register-tiled correlation, two c per lane ----
    int lane = tid & 63, wid = tid >> 6;
    int jp = lane & 7;              // output group: j = 8*jp + k
    int lg = lane >> 3;             // channel group within wave
    int j0 = 8 * jp;
    int c0 = wid * 8 + lg;          // 0..31
    int c1 = c0 + 32;               // 32..63 (skip >= 62)
    float acc[8];
    #pragma unroll
    for (int k = 0; k < 8; ++k) acc[k] = 0.f;

    corr_row(xt + c0 * XP + j0, Fl + c0 * FP, acc);
    if (c1 < CC)
        corr_row(xt + c1 * XP + j0, Fl + c1 * FP, acc);

    // reduce over lg (lane bits 3..5)
    #pragma unroll
    for (int k = 0; k < 8; ++k) {
        acc[k] += __shfl_xor(acc[k], 8);
        acc[k] += __shfl_xor(acc[k], 16);
        acc[k] += __shfl_xor(acc[k], 32);
    }
    if (lg == 0) {
        #pragma unroll
        for (int k = 0; k < 8; ++k) dpart[wid][j0 + k] = acc[k];
    }
    __syncthreads();

    if (tid < CC) {
        float d = dpart[0][tid] + dpart[1][tid] + dpart[2][tid] + dpart[3][tid];
        float v = d + *beff_p + adj[61 * CC + tid];
        adjt[tid] = 1.f / (1.f + __expf(-v));
    }
    __syncthreads();

    // wx[l] = sum_j adjt[j] * x[j][l]  (packed bf16 pairs: lane li owns l=2li, 2li+1)
    if (tid < 85) {
        float s0 = 0.f, s1 = 0.f;
        #pragma unroll 2
        for (int j = 0; j < CC; ++j) {
            unsigned v = ((const unsigned*)(xt + j * XP))[tid];
            float aj = adjt[j];
            s0 += aj * bflo(v);
            s1 += aj * bfhi(v);
        }
        wx[2 * tid] = s0;
        wx[2 * tid + 1] = s1;
    }
    __syncthreads();

    // g[f] = gcn_b[f] + sum_l wx[l] * gcn_w[l,f]   (l split over 4 thread groups)
    {
        int f = tid & 63, lq = tid >> 6;
        float s = 0.f;
        for (int l = lq; l < LL; l += 4) s += wx[l] * gcnw[l * OG + f];
        gpart[lq][f] = s;
    }
    __syncthreads();
    if (tid < OG)
        glds[tid] = gcnb[tid] + gpart[0][tid] + gpart[1][tid] + gpart[2][tid] + gpart[3][tid];
    __syncthreads();

    // per-gate gf-half pre-activations (+ all biases), transposed weights
    if (tid < 3 * OH) {
        int gate = tid >> 6, f = tid & 63;
        const float* Wt = Wtr + gate * OG * OH;
        const float* Wb = gate == 0 ? Wrb : (gate == 1 ? Wub : Wcb);
        const float* bb = gate == 0 ? br  : (gate == 1 ? bu  : bc);
        float s = Wb[f] + bb[f];
        #pragma unroll 4
        for (int i = 0; i < OG; ++i) s += glds[i] * Wt[i * OH + f];
        gates[((size_t)(gate * SS + t) * BB + b) * OH + f] = s;
    }
}

// ---------------- sequential GRU scan over t: one block per batch row ----------------
__global__ __launch_bounds__(256) void k_scan(
        const float* __restrict__ gates,
        const float* __restrict__ Wr, const float* __restrict__ Wu, const float* __restrict__ Wc,
        float* __restrict__ out) {
    __shared__ float hl[OH], rhl[OH];
    int b = blockIdx.x;
    int tid = threadIdx.x;
    int f = tid >> 2, q = tid & 3;
    float wr[16], wu[16], wc[16];
    #pragma unroll
    for (int i = 0; i < 16; ++i) {
        int col = OG + q * 16 + i;
        wr[i] = Wr[f * (OG + OH) + col];
        wu[i] = Wu[f * (OG + OH) + col];
        wc[i] = Wc[f * (OG + OH) + col];
    }
    float h = 0.f;
    if (tid < OH) hl[tid] = 0.f;
    __syncthreads();
    const float* Gr = gates;
    const float* Gu = gates + (size_t)SS * BB * OH;
    const float* Gc = gates + (size_t)2 * SS * BB * OH;
    for (int t = 0; t < SS; ++t) {
        float gr = Gr[((size_t)t * BB + b) * OH + f];
        float gu = Gu[((size_t)t * BB + b) * OH + f];
        float gc = Gc[((size_t)t * BB + b) * OH + f];
        float rv = 0.f, uv = 0.f;
        #pragma unroll
        for (int i = 0; i < 16; ++i) {
            float hv = hl[q * 16 + i];
            rv += wr[i] * hv;
            uv += wu[i] * hv;
        }
        rv += __shfl_xor(rv, 1); rv += __shfl_xor(rv, 2);
        uv += __shfl_xor(uv, 1); uv += __shfl_xor(uv, 2);
        float r = 1.f / (1.f + __expf(-(rv + gr)));
        float u = 1.f / (1.f + __expf(-(uv + gu)));
        if (q == 0) rhl[f] = r * h;
        __syncthreads();
        float cv = 0.f;
        #pragma unroll
        for (int i = 0; i < 16; ++i) cv += wc[i] * rhl[q * 16 + i];
        cv += __shfl_xor(cv, 1); cv += __shfl_xor(cv, 2);
        float cc = tanhf(cv + gc);
        if (q == 0) {
            h = u * h + (1.f - u) * cc;
            hl[f] = h;
        }
        __syncthreads();
    }
    if (q == 0) out[b * OH + f] = h;
}

extern "C" void kernel_launch(void* const* d_in, const int* in_sizes, int n_in,
                              void* d_out, int out_size, void* d_ws, size_t ws_size,
                              hipStream_t stream) {
    const float* x    = (const float*)d_in[0];
    const float* adj  = (const float*)d_in[1];
    const float* dw1w = (const float*)d_in[2];
    const float* dw1b = (const float*)d_in[3];
    const float* pw1w = (const float*)d_in[4];
    const float* pw1b = (const float*)d_in[5];
    const float* dw2w = (const float*)d_in[6];
    const float* dw2b = (const float*)d_in[7];
    const float* pw2w = (const float*)d_in[8];
    const float* pw2b = (const float*)d_in[9];
    const float* dw3w = (const float*)d_in[10];
    const float* dw3b = (const float*)d_in[11];
    const float* pw3w = (const float*)d_in[12];
    const float* pw3b = (const float*)d_in[13];
    const float* gcnw = (const float*)d_in[14];
    const float* gcnb = (const float*)d_in[15];
    const float* Wrw  = (const float*)d_in[16];
    const float* Wrb  = (const float*)d_in[17];
    const float* Wuw  = (const float*)d_in[18];
    const float* Wub  = (const float*)d_in[19];
    const float* Wcw  = (const float*)d_in[20];
    const float* Wcb  = (const float*)d_in[21];
    const float* br   = (const float*)d_in[22];
    const float* bu   = (const float*)d_in[23];
    const float* bc   = (const float*)d_in[24];
    float* out = (float*)d_out;

    // workspace layout (bytes)
    char* ws = (char*)d_ws;
    float* Tbuf           = (float*)(ws + 0);              // 365180 floats
    float* g23            = (float*)(ws + 1460736);        // 868 floats
    float* beff           = (float*)(ws + 1464320);        // 1 float
    unsigned short* Fbuf  = (unsigned short*)(ws + 1464576); // 6696 bf16 (16B aligned)
    float* gates          = (float*)(ws + 1491456);        // 1474560 floats
    float* Wt             = (float*)(ws + 7389696);        // 12288 floats
    (void)ws_size; (void)in_sizes; (void)n_in; (void)out_size;

    k_setup_T<<<CC * CC, 128, 0, stream>>>(dw1w, dw2w, pw1w, Tbuf);
    k_setup_g<<<1, 1024, 0, stream>>>(pw2w, pw3w, dw3w, dw1b, pw1w, pw1b,
                                      dw2w, dw2b, pw2b, dw3b, pw3b, g23, beff);
    k_setup_F<<<CC, 128, 0, stream>>>(Tbuf, g23, Fbuf);
    k_setup_Wt<<<3, 256, 0, stream>>>(Wrw, Wuw, Wcw, Wt);
    k_main<<<BB * SS, 256, 0, stream>>>(x, adj, Fbuf, beff, gcnw, gcnb, Wt,
                                        Wrb, br, Wub, bu, Wcb, bc, gates);
    k_scan<<<BB, 256, 0, stream>>>(gates, Wrw, Wuw, Wcw, out);
}